// Round 2
// baseline (5262.634 us; speedup 1.0000x reference)
//
#include <hip/hip_runtime.h>
#include <hip/hip_bf16.h>
#include <math.h>

// ---------------------------------------------------------------------------
// TalaThreadingLayer on MI355X (gfx950).
// prep(x+pe,bf16) -> casts -> xp GEMM -> persistent-WG GRU scan ->
// q/k/v GEMMs (reuse xp region) -> windowed attention -> beat GEMM(+resid)
// -> LN(thr) -> mix GEMM -> LN(final, PE recomputed) -> d_out
// Workspace: ~186 MiB. GRU h-exchange: 4-slot tagged ring in LLC (8B atomics).
// ---------------------------------------------------------------------------

using frag8   = __attribute__((ext_vector_type(8))) short;  // 8 bf16
using floatx4 = __attribute__((ext_vector_type(4))) float;  // mfma acc

#define B_ 4
#define T_ 2048
#define D_ 512
#define BT_ (B_ * T_)          // 8192

static __device__ __forceinline__ float bf2f(unsigned short u) {
    return __uint_as_float(((unsigned)u) << 16);
}
static __device__ __forceinline__ unsigned short f2bfbits(float f) {
    unsigned u = __float_as_uint(f);
    u = (u + 0x7FFF + ((u >> 16) & 1)) >> 16;   // RNE
    return (unsigned short)u;
}

// 0.5*pe + 0.5*tala at (t, d) — must match numpy fp32 semantics (accurate sinf/cosf)
static __device__ __forceinline__ float pe_tala(int t, int d) {
    int i2 = d >> 1;
    const float c0 = (float)(-9.210340371976184 / 512.0);   // -ln(1e4)/D
    float dv = expf((float)(2 * i2) * c0);
    float a  = (float)t * dv;
    float pe = (d & 1) ? cosf(a) : sinf(a);
    int kk = d >> 7;            // slot block 0..3 (slots=128)
    int s  = d & 127;
    int c  = kk + 5;            // CYCLES = [5,6,7,8]
    float phase = ((float)(t % c) / (float)c) * 6.2831854820251465f;
    float harm  = (float)((s & 63) + 1);
    float ta = (s < 64) ? sinf(phase * harm) : cosf(phase * harm);
    return 0.5f * pe + 0.5f * ta;
}

// ---------------------------------------------------------------- canary fill
__global__ void k_fill(float* __restrict__ out, int n) {
    int i = blockIdx.x * 256 + threadIdx.x;
    if (i < n) out[i] = 1234.5f;
}

// ---------------------------------------------------------------- prep x+pe -> bf16
__global__ void k_prep(const float* __restrict__ x, __hip_bfloat16* __restrict__ xinbf)
{
    int idx = blockIdx.x * 256 + threadIdx.x;
    if (idx >= B_ * T_ * D_) return;
    int d = idx & 511;
    int t = (idx >> 9) & 2047;
    xinbf[idx] = __float2bfloat16(x[idx] + pe_tala(t, d));
}

// ---------------------------------------------------------------- f32->bf16
__global__ void k_f2bf(const float* __restrict__ src, __hip_bfloat16* __restrict__ dst, int n)
{
    int i = blockIdx.x * 256 + threadIdx.x;
    if (i < n) dst[i] = __float2bfloat16(src[i]);
}

// ---------------------------------------------------------------- GEMM C = A * B^T
// A: (M,K) bf16 row-major. B: (N,K) bf16 row-major. Optional bias[n] fp32,
// optional resid bf16 at [row*N+col], out fp32 or bf16.
// 128x128 tile, BK=32, 256 threads, 16x16x32 bf16 MFMA. Sync LDS staging.
__global__ __launch_bounds__(256) void k_gemm(
    const __hip_bfloat16* __restrict__ A, const __hip_bfloat16* __restrict__ B,
    float* __restrict__ Cf, __hip_bfloat16* __restrict__ Cb,
    const float* __restrict__ bias, const __hip_bfloat16* __restrict__ resid,
    int M, int N, int K,
    long sA_, long sB_, long sC_, long sBias_)
{
    const int bz = blockIdx.z;
    A += (size_t)bz * sA_;
    B += (size_t)bz * sB_;
    const float* biasp = bias ? bias + (size_t)bz * sBias_ : (const float*)0;

    const int m0 = blockIdx.x * 128, n0 = blockIdx.y * 128;
    const int tid  = threadIdx.x;
    const int lane = tid & 63, wv = tid >> 6;
    const int wm = (wv >> 1) * 64, wn = (wv & 1) * 64;
    const int fr = lane & 15, quad = lane >> 4;

    __shared__ __align__(16) __hip_bfloat16 sAt[128 * 32];
    __shared__ __align__(16) __hip_bfloat16 sBt[128 * 32];

    floatx4 acc[4][4];
#pragma unroll
    for (int mi = 0; mi < 4; mi++)
#pragma unroll
        for (int ni = 0; ni < 4; ni++) acc[mi][ni] = (floatx4){0.f, 0.f, 0.f, 0.f};

    const int srow = tid >> 2;          // 0..63
    const int scol = (tid & 3) * 8;     // 0,8,16,24

    for (int k0 = 0; k0 < K; k0 += 32) {
        // global loads (independent, scheduled early)
        frag8 av0 = *(const frag8*)(A + (size_t)(m0 +      srow) * K + (k0 + scol));
        frag8 av1 = *(const frag8*)(A + (size_t)(m0 + 64 + srow) * K + (k0 + scol));
        frag8 bv0 = *(const frag8*)(B + (size_t)(n0 +      srow) * K + (k0 + scol));
        frag8 bv1 = *(const frag8*)(B + (size_t)(n0 + 64 + srow) * K + (k0 + scol));
        __syncthreads();   // prior iter's LDS reads done before overwrite
        *(frag8*)&sAt[(     srow) * 32 + scol] = av0;
        *(frag8*)&sAt[(64 + srow) * 32 + scol] = av1;
        *(frag8*)&sBt[(     srow) * 32 + scol] = bv0;
        *(frag8*)&sBt[(64 + srow) * 32 + scol] = bv1;
        __syncthreads();

        frag8 af[4], bfr[4];
#pragma unroll
        for (int mi = 0; mi < 4; mi++)
            af[mi] = *(const frag8*)&sAt[(wm + mi * 16 + fr) * 32 + quad * 8];
#pragma unroll
        for (int ni = 0; ni < 4; ni++)
            bfr[ni] = *(const frag8*)&sBt[(wn + ni * 16 + fr) * 32 + quad * 8];
#pragma unroll
        for (int mi = 0; mi < 4; mi++)
#pragma unroll
            for (int ni = 0; ni < 4; ni++)
                acc[mi][ni] = __builtin_amdgcn_mfma_f32_16x16x32_bf16(af[mi], bfr[ni], acc[mi][ni], 0, 0, 0);
    }

    const size_t coff = (size_t)bz * sC_;
#pragma unroll
    for (int mi = 0; mi < 4; mi++) {
#pragma unroll
        for (int ni = 0; ni < 4; ni++) {
            const int col = n0 + wn + ni * 16 + fr;
            const float bval = biasp ? biasp[col] : 0.f;
#pragma unroll
            for (int r2 = 0; r2 < 4; r2++) {
                const int row = m0 + wm + mi * 16 + quad * 4 + r2;
                const size_t ci = (size_t)row * N + col;
                float v = acc[mi][ni][r2] + bval;
                if (resid) v += bf2f(((const unsigned short*)resid)[ci]);
                if (Cf) Cf[coff + ci] = v;
                else    Cb[coff + ci] = __float2bfloat16(v);
            }
        }
    }
}

// ---------------------------------------------------------------- windowed attention
// One block: 16 query positions for one (k,b) pair. Window c = kk+5 <= 8.
__global__ __launch_bounds__(256) void k_attn(
    const __hip_bfloat16* __restrict__ Q, const __hip_bfloat16* __restrict__ Kx,
    const __hip_bfloat16* __restrict__ Vx, __hip_bfloat16* __restrict__ comb)
{
    const int pair = blockIdx.y;
    const int kk = pair >> 2;
    const int c = kk + 5;
    const int t0 = blockIdx.x * 16;
    const int tid = threadIdx.x, lane = tid & 63, wv = tid >> 6;

    __shared__ __align__(16) unsigned short kls[23 * 512];
    __shared__ __align__(16) unsigned short vls[23 * 512];

    const size_t qb = (size_t)pair * T_ * D_;
    for (int e = tid; e < 23 * 64; e += 256) {
        int r = e >> 6, ce = (e & 63) << 3;
        int s = t0 - 7 + r;
        frag8 kv = (frag8){0,0,0,0,0,0,0,0};
        frag8 vv = kv;
        if (s >= 0) {
            kv = *(const frag8*)((const unsigned short*)Kx + qb + (size_t)s * 512 + ce);
            vv = *(const frag8*)((const unsigned short*)Vx + qb + (size_t)s * 512 + ce);
        }
        *(frag8*)&kls[r * 512 + ce] = kv;
        *(frag8*)&vls[r * 512 + ce] = vv;
    }
    __syncthreads();

    const float scale = 0.044194173824159216f;  // 1/sqrt(512)
    for (int tt = wv; tt < 16; tt += 4) {
        const int t = t0 + tt;
        float qv[8];
        const unsigned short* qrow = (const unsigned short*)Q + qb + (size_t)t * 512 + lane * 8;
#pragma unroll
        for (int i = 0; i < 8; i++) qv[i] = bf2f(qrow[i]);

        float sc[8];
#pragma unroll
        for (int si = 0; si < 8; ++si) {
            const int s = t - 7 + si;
            const int r = tt + si;
            const unsigned short* krow = &kls[r * 512 + lane * 8];
            float p = 0.f;
#pragma unroll
            for (int i = 0; i < 8; i++) p += qv[i] * bf2f(krow[i]);
#pragma unroll
            for (int off = 1; off < 64; off <<= 1) p += __shfl_xor(p, off);
            const bool valid = (s >= 0) && (s >= t - c + 1);
            sc[si] = valid ? p * scale : -1e30f;
        }
        float mx = -1e30f;
#pragma unroll
        for (int si = 0; si < 8; ++si) mx = fmaxf(mx, sc[si]);
        float sum = 0.f;
#pragma unroll
        for (int si = 0; si < 8; ++si) { sc[si] = expf(sc[si] - mx); sum += sc[si]; }
        const float inv = 1.f / sum;

        float o[8] = {0,0,0,0,0,0,0,0};
#pragma unroll
        for (int si = 0; si < 8; ++si) {
            const int r = tt + si;
            const float w = sc[si] * inv;
            const unsigned short* vrow = &vls[r * 512 + lane * 8];
#pragma unroll
            for (int i = 0; i < 8; i++) o[i] += w * bf2f(vrow[i]);
        }
        frag8 ov;
#pragma unroll
        for (int i = 0; i < 8; i++) ov[i] = (short)f2bfbits(o[i]);
        *(frag8*)((unsigned short*)comb + ((size_t)pair * T_ + t) * 1024 + 512 + lane * 8) = ov;
    }
}

// ---------------------------------------------------------------- persistent GRU scan
// 256 blocks x 256 threads. pair = bid & 15 (keeps a pair's 16 WGs on one XCD
// under round-robin dispatch), wg = bid >> 4 owns dims [wg*32, wg*32+32).
// Thread (g=tid>>3, j=tid&7): dim d=wg*32+g, input slice j*64..+63 in VGPRs.
// h exchange: 4-slot ring of 8B words (tag=t+1)<<32 | bits(h). Safe: any WG at
// step t implies all 16 WGs finished step t-1, so slot t%4 (holding t-4) is dead.
__global__ __launch_bounds__(256, 1) void k_gru(
    const float* __restrict__ whh, const float* __restrict__ bhh,
    const __hip_bfloat16* __restrict__ xp,
    unsigned long long* __restrict__ hbuf,
    __hip_bfloat16* __restrict__ comb)
{
    const int pair = blockIdx.x & 15;
    const int wg   = blockIdx.x >> 4;
    const int kk   = pair >> 2;
    const int tid  = threadIdx.x;
    const int g = tid >> 3, j = tid & 7;
    const int d = wg * 32 + g;

    const float* wbase = whh + (size_t)kk * 1536 * 512;
    float4 wr4[16], wz4[16], wn4[16];
#pragma unroll
    for (int q = 0; q < 16; q++) {
        const int e = j * 64 + (q ^ (2 * j)) * 4;     // XOR-swizzled chunk order
        wr4[q] = *(const float4*)(wbase + (size_t)d * 512 + e);
        wz4[q] = *(const float4*)(wbase + (size_t)(512 + d) * 512 + e);
        wn4[q] = *(const float4*)(wbase + (size_t)(1024 + d) * 512 + e);
    }
    const float bhr = bhh[kk * 1536 + d];
    const float bhz = bhh[kk * 1536 + 512 + d];
    const float bhn = bhh[kk * 1536 + 1024 + d];

    const unsigned short* xbase = (const unsigned short*)xp + (size_t)pair * T_ * 1536;
    __shared__ __align__(16) float h_lds[2][512];

    int bail = 0;   // global spin budget: guarantees termination even if broken
    for (int t = 0; t < T_; ++t) {
        const int par = t & 1;
        const unsigned short* xrow = xbase + (size_t)t * 1536;
        const float xr = bf2f(xrow[d]);
        const float xz = bf2f(xrow[512 + d]);
        const float xn = bf2f(xrow[1024 + d]);

        if (t == 0) {
            ((float2*)h_lds[0])[tid] = make_float2(0.f, 0.f);
        } else {
            unsigned long long* hrow = hbuf + ((size_t)pair * 4 + ((t - 1) & 3)) * 512;
            const unsigned tag = (unsigned)t;  // (t-1)+1
            unsigned long long a0, a1;
            for (;;) {
                a0 = __hip_atomic_load(&hrow[2 * tid],     __ATOMIC_RELAXED, __HIP_MEMORY_SCOPE_AGENT);
                a1 = __hip_atomic_load(&hrow[2 * tid + 1], __ATOMIC_RELAXED, __HIP_MEMORY_SCOPE_AGENT);
                if ((unsigned)(a0 >> 32) == tag && (unsigned)(a1 >> 32) == tag) break;
                if (++bail > 16000000) break;
            }
            ((float2*)h_lds[par])[tid] =
                make_float2(__uint_as_float((unsigned)a0), __uint_as_float((unsigned)a1));
        }
        __syncthreads();

        float ar = 0.f, az = 0.f, an = 0.f;
#pragma unroll
        for (int q = 0; q < 16; q++) {
            const int e = j * 64 + (q ^ (2 * j)) * 4;
            const float4 h4 = *(const float4*)&h_lds[par][e];
            ar += wr4[q].x * h4.x + wr4[q].y * h4.y + wr4[q].z * h4.z + wr4[q].w * h4.w;
            az += wz4[q].x * h4.x + wz4[q].y * h4.y + wz4[q].z * h4.z + wz4[q].w * h4.w;
            an += wn4[q].x * h4.x + wn4[q].y * h4.y + wn4[q].z * h4.z + wn4[q].w * h4.w;
        }
#pragma unroll
        for (int off = 1; off < 8; off <<= 1) {
            ar += __shfl_xor(ar, off);
            az += __shfl_xor(az, off);
            an += __shfl_xor(an, off);
        }
        const float r = 1.f / (1.f + expf(-(xr + ar + bhr)));
        const float z = 1.f / (1.f + expf(-(xz + az + bhz)));
        const float n = tanhf(xn + r * (an + bhn));
        const float hprev = h_lds[par][d];
        const float hnew = (1.f - z) * n + z * hprev;

        if (j == 0) {
            const unsigned long long u =
                ((unsigned long long)(unsigned)(t + 1) << 32) | (unsigned long long)__float_as_uint(hnew);
            __hip_atomic_store(&hbuf[((size_t)pair * 4 + (t & 3)) * 512 + d], u,
                               __ATOMIC_RELAXED, __HIP_MEMORY_SCOPE_AGENT);
            comb[((size_t)pair * T_ + t) * 1024 + d] = __float2bfloat16(hnew);
        }
        // no trailing barrier: h_lds is parity double-buffered; the next
        // __syncthreads (full LDS fence) orders step t reads vs step t+2 writes
    }
}

// ---------------------------------------------------------------- LN over thr -> merged bf16
__global__ void k_ln_thr(const __hip_bfloat16* __restrict__ bp,
                         const float* __restrict__ gg, const float* __restrict__ bb2,
                         __hip_bfloat16* __restrict__ thrm)
{
    const int kk = blockIdx.y;
    const int lane = threadIdx.x & 63, wv = threadIdx.x >> 6;
    float g8[8], b8[8];
#pragma unroll
    for (int i = 0; i < 8; i++) {
        g8[i] = gg[kk * 512 + lane * 8 + i];
        b8[i] = bb2[kk * 512 + lane * 8 + i];
    }
    for (int rr = 0; rr < 8; ++rr) {
        const int bt = blockIdx.x * 32 + wv * 8 + rr;
        const unsigned short* row = (const unsigned short*)bp + ((size_t)kk * BT_ + bt) * 512 + lane * 8;
        float v[8];
#pragma unroll
        for (int i = 0; i < 8; i++) v[i] = bf2f(row[i]);
        float s = 0.f, s2 = 0.f;
#pragma unroll
        for (int i = 0; i < 8; i++) { s += v[i]; s2 += v[i] * v[i]; }
#pragma unroll
        for (int off = 1; off < 64; off <<= 1) { s += __shfl_xor(s, off); s2 += __shfl_xor(s2, off); }
        const float mean = s * (1.f / 512.f);
        const float var = s2 * (1.f / 512.f) - mean * mean;
        const float rs = 1.f / sqrtf(var + 1e-5f);
        frag8 ov;
#pragma unroll
        for (int i = 0; i < 8; i++) ov[i] = (short)f2bfbits((v[i] - mean) * rs * g8[i] + b8[i]);
        *(frag8*)((unsigned short*)thrm + (size_t)bt * 2048 + kk * 512 + lane * 8) = ov;
    }
}

// ---------------------------------------------------------------- final LN -> d_out fp32
// xin = x + pe recomputed in fp32 here (saves a 16.8 MB buffer).
__global__ void k_ln_fin(const float* __restrict__ mo, const float* __restrict__ x,
                         const float* __restrict__ gg, const float* __restrict__ bb2,
                         float* __restrict__ out)
{
    const int lane = threadIdx.x & 63, wv = threadIdx.x >> 6;
    float g8[8], b8[8];
#pragma unroll
    for (int i = 0; i < 8; i++) {
        g8[i] = gg[lane * 8 + i];
        b8[i] = bb2[lane * 8 + i];
    }
    for (int rr = 0; rr < 8; ++rr) {
        const int bt = blockIdx.x * 32 + wv * 8 + rr;
        const int t = bt & 2047;
        const float* r1 = mo + (size_t)bt * 512 + lane * 8;
        const float* r2 = x + (size_t)bt * 512 + lane * 8;
        float v[8];
#pragma unroll
        for (int i = 0; i < 8; i++) v[i] = r1[i] + r2[i] + pe_tala(t, lane * 8 + i);
        float s = 0.f, s2 = 0.f;
#pragma unroll
        for (int i = 0; i < 8; i++) { s += v[i]; s2 += v[i] * v[i]; }
#pragma unroll
        for (int off = 1; off < 64; off <<= 1) { s += __shfl_xor(s, off); s2 += __shfl_xor(s2, off); }
        const float mean = s * (1.f / 512.f);
        const float var = s2 * (1.f / 512.f) - mean * mean;
        const float rs = 1.f / sqrtf(var + 1e-5f);
#pragma unroll
        for (int i = 0; i < 8; i++)
            out[(size_t)bt * 512 + lane * 8 + i] = (v[i] - mean) * rs * g8[i] + b8[i];
    }
}

// ---------------------------------------------------------------- launcher
extern "C" void kernel_launch(void* const* d_in, const int* in_sizes, int n_in,
                              void* d_out, int out_size, void* d_ws, size_t ws_size,
                              hipStream_t stream)
{
    const float* x     = (const float*)d_in[0];
    const float* wih   = (const float*)d_in[1];
    const float* whh   = (const float*)d_in[2];
    const float* bih   = (const float*)d_in[3];
    const float* bhh   = (const float*)d_in[4];
    const float* wq    = (const float*)d_in[5];
    const float* wk    = (const float*)d_in[6];
    const float* wv    = (const float*)d_in[7];
    const float* wbeat = (const float*)d_in[8];
    const float* ng    = (const float*)d_in[9];
    const float* nb    = (const float*)d_in[10];
    const float* wmix  = (const float*)d_in[11];
    const float* bng   = (const float*)d_in[12];
    const float* bnb   = (const float*)d_in[13];

    char* ws = (char*)d_ws;
    size_t off = 0;
    auto alloc = [&](size_t b) { size_t o = off; off += (b + 255) & ~(size_t)255; return o; };

    const size_t XINBF  = alloc((size_t)BT_ * 512 * 2);        //  8.4 MB
    const size_t WIHBF  = alloc((size_t)4 * 1536 * 512 * 2);   //  6.3 MB
    const size_t WQBF   = alloc((size_t)4 * 512 * 512 * 2);
    const size_t WKBF   = alloc((size_t)4 * 512 * 512 * 2);
    const size_t WVBF   = alloc((size_t)4 * 512 * 512 * 2);
    const size_t WBEATBF= alloc((size_t)4 * 512 * 1024 * 2);
    const size_t WMIXBF = alloc((size_t)512 * 2048 * 2);
    const size_t HBUF   = alloc((size_t)16 * 4 * 512 * 8);     //  256 KB ring
    const size_t COMB   = alloc((size_t)4 * BT_ * 1024 * 2);   // 67.1 MB
    const size_t BIG    = alloc((size_t)4 * BT_ * 1536 * 2);   // 100.7 MB (xp -> QKV -> beat/thr/mix)
    const size_t NEED   = off;                                  // ~195.3 MB total

    // BIG overlays (phases are stream-serialized):
    const size_t XPO   = BIG;                   // phase A: xp (4,8192,1536) bf16
    const size_t QO    = BIG;                   // phase B: Q (4,8192,512) bf16
    const size_t KO    = BIG + 33554432;        //          K
    const size_t VO    = BIG + 67108864;        //          V
    const size_t BEATO = BIG;                   // phase C: beat (4,8192,512) bf16
    const size_t THRO  = BIG + 33554432;        //          merged thr (8192,2048) bf16
    const size_t MIXO  = BIG + 67108864;        //          mix out (8192,512) fp32

    if (ws_size < NEED) {
        // canary: distinguishable failure mode (absmax ~1233 => ws too small)
        k_fill<<<(out_size + 255) / 256, 256, 0, stream>>>((float*)d_out, out_size);
        return;
    }

    // GRU ring must start without valid tags
    hipMemsetAsync(ws + HBUF, 0, (size_t)16 * 4 * 512 * 8, stream);

    // 1. x + positional encoding (bf16)
    k_prep<<<(B_ * T_ * D_ + 255) / 256, 256, 0, stream>>>(x, (__hip_bfloat16*)(ws + XINBF));

    // 2. weight casts to bf16
    auto cast = [&](const float* s, size_t o, int n) {
        k_f2bf<<<(n + 255) / 256, 256, 0, stream>>>(s, (__hip_bfloat16*)(ws + o), n);
    };
    cast(wih,   WIHBF,  4 * 1536 * 512);
    cast(wq,    WQBF,   4 * 512 * 512);
    cast(wk,    WKBF,   4 * 512 * 512);
    cast(wv,    WVBF,   4 * 512 * 512);
    cast(wbeat, WBEATBF,4 * 512 * 1024);
    cast(wmix,  WMIXBF, 512 * 2048);

    const __hip_bfloat16* xinbf = (const __hip_bfloat16*)(ws + XINBF);

    // 3. xp = wih . xin + bih   (4, 8192, 1536) bf16
    k_gemm<<<dim3(BT_ / 128, 1536 / 128, 4), 256, 0, stream>>>(
        xinbf, (const __hip_bfloat16*)(ws + WIHBF),
        nullptr, (__hip_bfloat16*)(ws + XPO),
        bih, nullptr, BT_, 1536, 512,
        0, (long)1536 * 512, (long)BT_ * 1536, 1536);

    // 4. GRU scan -> comb[.., 0:512]   (consumes xp)
    k_gru<<<256, 256, 0, stream>>>(
        whh, bhh, (const __hip_bfloat16*)(ws + XPO),
        (unsigned long long*)(ws + HBUF), (__hip_bfloat16*)(ws + COMB));

    // 5. q/k/v projections (reuse xp region; xp is dead now)
    k_gemm<<<dim3(BT_ / 128, 4, 4), 256, 0, stream>>>(
        xinbf, (const __hip_bfloat16*)(ws + WQBF), nullptr, (__hip_bfloat16*)(ws + QO),
        nullptr, nullptr, BT_, 512, 512, 0, (long)512 * 512, (long)BT_ * 512, 0);
    k_gemm<<<dim3(BT_ / 128, 4, 4), 256, 0, stream>>>(
        xinbf, (const __hip_bfloat16*)(ws + WKBF), nullptr, (__hip_bfloat16*)(ws + KO),
        nullptr, nullptr, BT_, 512, 512, 0, (long)512 * 512, (long)BT_ * 512, 0);
    k_gemm<<<dim3(BT_ / 128, 4, 4), 256, 0, stream>>>(
        xinbf, (const __hip_bfloat16*)(ws + WVBF), nullptr, (__hip_bfloat16*)(ws + VO),
        nullptr, nullptr, BT_, 512, 512, 0, (long)512 * 512, (long)BT_ * 512, 0);

    // 6. windowed attention -> comb[.., 512:1024]
    k_attn<<<dim3(T_ / 16, 16), 256, 0, stream>>>(
        (const __hip_bfloat16*)(ws + QO), (const __hip_bfloat16*)(ws + KO),
        (const __hip_bfloat16*)(ws + VO), (__hip_bfloat16*)(ws + COMB));

    // 7. beat = w_beat . comb + xin  -> bf16 (overwrites Q region)
    k_gemm<<<dim3(BT_ / 128, 4, 4), 256, 0, stream>>>(
        (const __hip_bfloat16*)(ws + COMB), (const __hip_bfloat16*)(ws + WBEATBF),
        nullptr, (__hip_bfloat16*)(ws + BEATO),
        nullptr, xinbf, BT_, 512, 1024,
        (long)BT_ * 1024, (long)512 * 1024, (long)BT_ * 512, 0);

    // 8. per-thread LayerNorm -> merged (8192, 2048) bf16 (overwrites K region)
    k_ln_thr<<<dim3(BT_ / 32, 4), 256, 0, stream>>>(
        (const __hip_bfloat16*)(ws + BEATO), ng, nb, (__hip_bfloat16*)(ws + THRO));

    // 9. out = w_mix . merged (fp32, overwrites V region)
    k_gemm<<<dim3(BT_ / 128, 4, 1), 256, 0, stream>>>(
        (const __hip_bfloat16*)(ws + THRO), (const __hip_bfloat16*)(ws + WMIXBF),
        (float*)(ws + MIXO), nullptr,
        nullptr, nullptr, BT_, 512, 2048, 0, 0, 0, 0);

    // 10. final LayerNorm(out + x + pe) -> d_out
    k_ln_fin<<<BT_ / 32, 256, 0, stream>>>(
        (const float*)(ws + MIXO), x, bng, bnb, (float*)d_out);
}

// Round 3
// 3749.643 us; speedup vs baseline: 1.4035x; 1.4035x over previous
//
#include <hip/hip_runtime.h>
#include <hip/hip_bf16.h>
#include <math.h>

// ---------------------------------------------------------------------------
// TalaThreadingLayer on MI355X (gfx950).
// prep(x+pe,bf16) -> casts -> xp GEMM -> persistent-WG GRU scan ->
// q/k/v GEMMs (reuse xp region) -> windowed attention -> beat GEMM(+resid)
// -> LN(thr) -> mix GEMM -> LN(final, PE recomputed) -> d_out
// GRU: 256 blocks x 512 thr; 16 thr/dim; 96 fp32 weights per thread in VGPRs
// (launch_bounds(512,2) -> 256-reg budget, no scratch); h exchange = one
// tagged 8B LLC word per thread, 4-slot ring.
// ---------------------------------------------------------------------------

using frag8   = __attribute__((ext_vector_type(8))) short;  // 8 bf16
using floatx4 = __attribute__((ext_vector_type(4))) float;  // mfma acc

#define B_ 4
#define T_ 2048
#define D_ 512
#define BT_ (B_ * T_)          // 8192

static __device__ __forceinline__ float bf2f(unsigned short u) {
    return __uint_as_float(((unsigned)u) << 16);
}
static __device__ __forceinline__ unsigned short f2bfbits(float f) {
    unsigned u = __float_as_uint(f);
    u = (u + 0x7FFF + ((u >> 16) & 1)) >> 16;   // RNE
    return (unsigned short)u;
}

// 0.5*pe + 0.5*tala at (t, d) — matches numpy fp32 semantics
static __device__ __forceinline__ float pe_tala(int t, int d) {
    int i2 = d >> 1;
    const float c0 = (float)(-9.210340371976184 / 512.0);   // -ln(1e4)/D
    float dv = expf((float)(2 * i2) * c0);
    float a  = (float)t * dv;
    float pe = (d & 1) ? cosf(a) : sinf(a);
    int kk = d >> 7;            // slot block 0..3 (slots=128)
    int s  = d & 127;
    int c  = kk + 5;            // CYCLES = [5,6,7,8]
    float phase = ((float)(t % c) / (float)c) * 6.2831854820251465f;
    float harm  = (float)((s & 63) + 1);
    float ta = (s < 64) ? sinf(phase * harm) : cosf(phase * harm);
    return 0.5f * pe + 0.5f * ta;
}

// ---------------------------------------------------------------- canary fill
__global__ void k_fill(float* __restrict__ out, int n) {
    int i = blockIdx.x * 256 + threadIdx.x;
    if (i < n) out[i] = 1234.5f;
}

// ---------------------------------------------------------------- prep x+pe -> bf16
__global__ void k_prep(const float* __restrict__ x, __hip_bfloat16* __restrict__ xinbf)
{
    int idx = blockIdx.x * 256 + threadIdx.x;
    if (idx >= B_ * T_ * D_) return;
    int d = idx & 511;
    int t = (idx >> 9) & 2047;
    xinbf[idx] = __float2bfloat16(x[idx] + pe_tala(t, d));
}

// ---------------------------------------------------------------- f32->bf16
__global__ void k_f2bf(const float* __restrict__ src, __hip_bfloat16* __restrict__ dst, int n)
{
    int i = blockIdx.x * 256 + threadIdx.x;
    if (i < n) dst[i] = __float2bfloat16(src[i]);
}

// ---------------------------------------------------------------- GEMM C = A * B^T
// A: (M,K) bf16 row-major. B: (N,K) bf16 row-major. Optional bias[n] fp32,
// optional resid bf16 at [row*N+col], out fp32 or bf16.
// 128x128 tile, BK=32, 256 threads, 16x16x32 bf16 MFMA. Sync LDS staging.
__global__ __launch_bounds__(256) void k_gemm(
    const __hip_bfloat16* __restrict__ A, const __hip_bfloat16* __restrict__ B,
    float* __restrict__ Cf, __hip_bfloat16* __restrict__ Cb,
    const float* __restrict__ bias, const __hip_bfloat16* __restrict__ resid,
    int M, int N, int K,
    long sA_, long sB_, long sC_, long sBias_)
{
    const int bz = blockIdx.z;
    A += (size_t)bz * sA_;
    B += (size_t)bz * sB_;
    const float* biasp = bias ? bias + (size_t)bz * sBias_ : (const float*)0;

    const int m0 = blockIdx.x * 128, n0 = blockIdx.y * 128;
    const int tid  = threadIdx.x;
    const int lane = tid & 63, wv = tid >> 6;
    const int wm = (wv >> 1) * 64, wn = (wv & 1) * 64;
    const int fr = lane & 15, quad = lane >> 4;

    __shared__ __align__(16) __hip_bfloat16 sAt[128 * 32];
    __shared__ __align__(16) __hip_bfloat16 sBt[128 * 32];

    floatx4 acc[4][4];
#pragma unroll
    for (int mi = 0; mi < 4; mi++)
#pragma unroll
        for (int ni = 0; ni < 4; ni++) acc[mi][ni] = (floatx4){0.f, 0.f, 0.f, 0.f};

    const int srow = tid >> 2;          // 0..63
    const int scol = (tid & 3) * 8;     // 0,8,16,24

    for (int k0 = 0; k0 < K; k0 += 32) {
        frag8 av0 = *(const frag8*)(A + (size_t)(m0 +      srow) * K + (k0 + scol));
        frag8 av1 = *(const frag8*)(A + (size_t)(m0 + 64 + srow) * K + (k0 + scol));
        frag8 bv0 = *(const frag8*)(B + (size_t)(n0 +      srow) * K + (k0 + scol));
        frag8 bv1 = *(const frag8*)(B + (size_t)(n0 + 64 + srow) * K + (k0 + scol));
        __syncthreads();
        *(frag8*)&sAt[(     srow) * 32 + scol] = av0;
        *(frag8*)&sAt[(64 + srow) * 32 + scol] = av1;
        *(frag8*)&sBt[(     srow) * 32 + scol] = bv0;
        *(frag8*)&sBt[(64 + srow) * 32 + scol] = bv1;
        __syncthreads();

        frag8 af[4], bfr[4];
#pragma unroll
        for (int mi = 0; mi < 4; mi++)
            af[mi] = *(const frag8*)&sAt[(wm + mi * 16 + fr) * 32 + quad * 8];
#pragma unroll
        for (int ni = 0; ni < 4; ni++)
            bfr[ni] = *(const frag8*)&sBt[(wn + ni * 16 + fr) * 32 + quad * 8];
#pragma unroll
        for (int mi = 0; mi < 4; mi++)
#pragma unroll
            for (int ni = 0; ni < 4; ni++)
                acc[mi][ni] = __builtin_amdgcn_mfma_f32_16x16x32_bf16(af[mi], bfr[ni], acc[mi][ni], 0, 0, 0);
    }

    const size_t coff = (size_t)bz * sC_;
#pragma unroll
    for (int mi = 0; mi < 4; mi++) {
#pragma unroll
        for (int ni = 0; ni < 4; ni++) {
            const int col = n0 + wn + ni * 16 + fr;
            const float bval = biasp ? biasp[col] : 0.f;
#pragma unroll
            for (int r2 = 0; r2 < 4; r2++) {
                const int row = m0 + wm + mi * 16 + quad * 4 + r2;
                const size_t ci = (size_t)row * N + col;
                float v = acc[mi][ni][r2] + bval;
                if (resid) v += bf2f(((const unsigned short*)resid)[ci]);
                if (Cf) Cf[coff + ci] = v;
                else    Cb[coff + ci] = __float2bfloat16(v);
            }
        }
    }
}

// ---------------------------------------------------------------- windowed attention
__global__ __launch_bounds__(256) void k_attn(
    const __hip_bfloat16* __restrict__ Q, const __hip_bfloat16* __restrict__ Kx,
    const __hip_bfloat16* __restrict__ Vx, __hip_bfloat16* __restrict__ comb)
{
    const int pair = blockIdx.y;
    const int kk = pair >> 2;
    const int c = kk + 5;
    const int t0 = blockIdx.x * 16;
    const int tid = threadIdx.x, lane = tid & 63, wv = tid >> 6;

    __shared__ __align__(16) unsigned short kls[23 * 512];
    __shared__ __align__(16) unsigned short vls[23 * 512];

    const size_t qb = (size_t)pair * T_ * D_;
    for (int e = tid; e < 23 * 64; e += 256) {
        int r = e >> 6, ce = (e & 63) << 3;
        int s = t0 - 7 + r;
        frag8 kv = (frag8){0,0,0,0,0,0,0,0};
        frag8 vv = kv;
        if (s >= 0) {
            kv = *(const frag8*)((const unsigned short*)Kx + qb + (size_t)s * 512 + ce);
            vv = *(const frag8*)((const unsigned short*)Vx + qb + (size_t)s * 512 + ce);
        }
        *(frag8*)&kls[r * 512 + ce] = kv;
        *(frag8*)&vls[r * 512 + ce] = vv;
    }
    __syncthreads();

    const float scale = 0.044194173824159216f;  // 1/sqrt(512)
    for (int tt = wv; tt < 16; tt += 4) {
        const int t = t0 + tt;
        float qv[8];
        const unsigned short* qrow = (const unsigned short*)Q + qb + (size_t)t * 512 + lane * 8;
#pragma unroll
        for (int i = 0; i < 8; i++) qv[i] = bf2f(qrow[i]);

        float sc[8];
#pragma unroll
        for (int si = 0; si < 8; ++si) {
            const int s = t - 7 + si;
            const int r = tt + si;
            const unsigned short* krow = &kls[r * 512 + lane * 8];
            float p = 0.f;
#pragma unroll
            for (int i = 0; i < 8; i++) p += qv[i] * bf2f(krow[i]);
#pragma unroll
            for (int off = 1; off < 64; off <<= 1) p += __shfl_xor(p, off);
            const bool valid = (s >= 0) && (s >= t - c + 1);
            sc[si] = valid ? p * scale : -1e30f;
        }
        float mx = -1e30f;
#pragma unroll
        for (int si = 0; si < 8; ++si) mx = fmaxf(mx, sc[si]);
        float sum = 0.f;
#pragma unroll
        for (int si = 0; si < 8; ++si) { sc[si] = expf(sc[si] - mx); sum += sc[si]; }
        const float inv = 1.f / sum;

        float o[8] = {0,0,0,0,0,0,0,0};
#pragma unroll
        for (int si = 0; si < 8; ++si) {
            const int r = tt + si;
            const float w = sc[si] * inv;
            const unsigned short* vrow = &vls[r * 512 + lane * 8];
#pragma unroll
            for (int i = 0; i < 8; i++) o[i] += w * bf2f(vrow[i]);
        }
        frag8 ov;
#pragma unroll
        for (int i = 0; i < 8; i++) ov[i] = (short)f2bfbits(o[i]);
        *(frag8*)((unsigned short*)comb + ((size_t)pair * T_ + t) * 1024 + 512 + lane * 8) = ov;
    }
}

// ---------------------------------------------------------------- persistent GRU scan
// 256 blocks x 512 threads, 1 block/CU. pair = bid & 15 ; wg = bid >> 4 owns
// dims [wg*32, wg*32+32). Thread (g=tid>>4, j=tid&15): dim d=wg*32+g, input
// slice j*32..+31 -> 96 fp32 weights/thread, resident in VGPRs
// (launch_bounds(512,2) -> 256-reg budget; round-2 run spilled at 128).
// h exchange: thread tid owns word tid of the pair's 512-dim h row in a
// 4-slot LLC ring of 8B (tag=t+1)<<32|bits(h) words.
__global__ __launch_bounds__(512, 2) void k_gru(
    const float* __restrict__ whh, const float* __restrict__ bhh,
    const __hip_bfloat16* __restrict__ xp,
    unsigned long long* __restrict__ hbuf,
    __hip_bfloat16* __restrict__ comb)
{
    const int pair = blockIdx.x & 15;
    const int wg   = blockIdx.x >> 4;
    const int kk   = pair >> 2;
    const int tid  = threadIdx.x;
    const int g = tid >> 4, j = tid & 15;
    const int d = wg * 32 + g;

    const float* wbase = whh + (size_t)kk * 1536 * 512;
    float4 wr4[8], wz4[8], wn4[8];
#pragma unroll
    for (int q = 0; q < 8; q++) {
        const int e = j * 32 + ((q ^ j) & 7) * 4;     // XOR-swizzle: 2-way LDS conflict max
        wr4[q] = *(const float4*)(wbase + (size_t)d * 512 + e);
        wz4[q] = *(const float4*)(wbase + (size_t)(512 + d) * 512 + e);
        wn4[q] = *(const float4*)(wbase + (size_t)(1024 + d) * 512 + e);
    }
    const float bhr = bhh[kk * 1536 + d];
    const float bhz = bhh[kk * 1536 + 512 + d];
    const float bhn = bhh[kk * 1536 + 1024 + d];

    const unsigned short* xbase = (const unsigned short*)xp + (size_t)pair * T_ * 1536;
    __shared__ __align__(16) float h_lds[2][512];

    int bail = 0;   // cumulative spin budget: guarantees termination if broken
    for (int t = 0; t < T_; ++t) {
        const int par = t & 1;
        const unsigned short* xrow = xbase + (size_t)t * 1536;
        float xr = 0.f, xz = 0.f, xn = 0.f;
        if (j == 0) {                      // only reduction owners need x-gates
            xr = bf2f(xrow[d]);
            xz = bf2f(xrow[512 + d]);
            xn = bf2f(xrow[1024 + d]);
        }

        if (t == 0) {
            h_lds[0][tid] = 0.f;
        } else {
            unsigned long long* hrow = hbuf + ((size_t)pair * 4 + ((t - 1) & 3)) * 512;
            const unsigned tag = (unsigned)t;  // (t-1)+1
            unsigned long long a0;
            for (;;) {
                a0 = __hip_atomic_load(&hrow[tid], __ATOMIC_RELAXED, __HIP_MEMORY_SCOPE_AGENT);
                if ((unsigned)(a0 >> 32) == tag) break;
                if (++bail > 2000000) break;
            }
            h_lds[par][tid] = __uint_as_float((unsigned)a0);
        }
        __syncthreads();

        float ar = 0.f, az = 0.f, an = 0.f;
#pragma unroll
        for (int q = 0; q < 8; q++) {
            const int e = j * 32 + ((q ^ j) & 7) * 4;
            const float4 h4 = *(const float4*)&h_lds[par][e];
            ar += wr4[q].x * h4.x + wr4[q].y * h4.y + wr4[q].z * h4.z + wr4[q].w * h4.w;
            az += wz4[q].x * h4.x + wz4[q].y * h4.y + wz4[q].z * h4.z + wz4[q].w * h4.w;
            an += wn4[q].x * h4.x + wn4[q].y * h4.y + wn4[q].z * h4.z + wn4[q].w * h4.w;
        }
#pragma unroll
        for (int off = 1; off < 16; off <<= 1) {
            ar += __shfl_xor(ar, off);
            az += __shfl_xor(az, off);
            an += __shfl_xor(an, off);
        }
        if (j == 0) {
            const float r = 1.f / (1.f + expf(-(xr + ar + bhr)));
            const float z = 1.f / (1.f + expf(-(xz + az + bhz)));
            const float n = tanhf(xn + r * (an + bhn));
            const float hprev = h_lds[par][d];
            const float hnew = (1.f - z) * n + z * hprev;
            const unsigned long long u =
                ((unsigned long long)(unsigned)(t + 1) << 32) | (unsigned long long)__float_as_uint(hnew);
            __hip_atomic_store(&hbuf[((size_t)pair * 4 + (t & 3)) * 512 + d], u,
                               __ATOMIC_RELAXED, __HIP_MEMORY_SCOPE_AGENT);
            comb[((size_t)pair * T_ + t) * 1024 + d] = __float2bfloat16(hnew);
        }
        // no trailing barrier: h_lds parity double-buffer + next barrier orders reuse
    }
}

// ---------------------------------------------------------------- LN over thr -> merged bf16
__global__ void k_ln_thr(const __hip_bfloat16* __restrict__ bp,
                         const float* __restrict__ gg, const float* __restrict__ bb2,
                         __hip_bfloat16* __restrict__ thrm)
{
    const int kk = blockIdx.y;
    const int lane = threadIdx.x & 63, wv = threadIdx.x >> 6;
    float g8[8], b8[8];
#pragma unroll
    for (int i = 0; i < 8; i++) {
        g8[i] = gg[kk * 512 + lane * 8 + i];
        b8[i] = bb2[kk * 512 + lane * 8 + i];
    }
    for (int rr = 0; rr < 8; ++rr) {
        const int bt = blockIdx.x * 32 + wv * 8 + rr;
        const unsigned short* row = (const unsigned short*)bp + ((size_t)kk * BT_ + bt) * 512 + lane * 8;
        float v[8];
#pragma unroll
        for (int i = 0; i < 8; i++) v[i] = bf2f(row[i]);
        float s = 0.f, s2 = 0.f;
#pragma unroll
        for (int i = 0; i < 8; i++) { s += v[i]; s2 += v[i] * v[i]; }
#pragma unroll
        for (int off = 1; off < 64; off <<= 1) { s += __shfl_xor(s, off); s2 += __shfl_xor(s2, off); }
        const float mean = s * (1.f / 512.f);
        const float var = s2 * (1.f / 512.f) - mean * mean;
        const float rs = 1.f / sqrtf(var + 1e-5f);
        frag8 ov;
#pragma unroll
        for (int i = 0; i < 8; i++) ov[i] = (short)f2bfbits((v[i] - mean) * rs * g8[i] + b8[i]);
        *(frag8*)((unsigned short*)thrm + (size_t)bt * 2048 + kk * 512 + lane * 8) = ov;
    }
}

// ---------------------------------------------------------------- final LN -> d_out fp32
__global__ void k_ln_fin(const float* __restrict__ mo, const float* __restrict__ x,
                         const float* __restrict__ gg, const float* __restrict__ bb2,
                         float* __restrict__ out)
{
    const int lane = threadIdx.x & 63, wv = threadIdx.x >> 6;
    float g8[8], b8[8];
#pragma unroll
    for (int i = 0; i < 8; i++) {
        g8[i] = gg[lane * 8 + i];
        b8[i] = bb2[lane * 8 + i];
    }
    for (int rr = 0; rr < 8; ++rr) {
        const int bt = blockIdx.x * 32 + wv * 8 + rr;
        const int t = bt & 2047;
        const float* r1 = mo + (size_t)bt * 512 + lane * 8;
        const float* r2 = x + (size_t)bt * 512 + lane * 8;
        float v[8];
#pragma unroll
        for (int i = 0; i < 8; i++) v[i] = r1[i] + r2[i] + pe_tala(t, lane * 8 + i);
        float s = 0.f, s2 = 0.f;
#pragma unroll
        for (int i = 0; i < 8; i++) { s += v[i]; s2 += v[i] * v[i]; }
#pragma unroll
        for (int off = 1; off < 64; off <<= 1) { s += __shfl_xor(s, off); s2 += __shfl_xor(s2, off); }
        const float mean = s * (1.f / 512.f);
        const float var = s2 * (1.f / 512.f) - mean * mean;
        const float rs = 1.f / sqrtf(var + 1e-5f);
#pragma unroll
        for (int i = 0; i < 8; i++)
            out[(size_t)bt * 512 + lane * 8 + i] = (v[i] - mean) * rs * g8[i] + b8[i];
    }
}

// ---------------------------------------------------------------- launcher
extern "C" void kernel_launch(void* const* d_in, const int* in_sizes, int n_in,
                              void* d_out, int out_size, void* d_ws, size_t ws_size,
                              hipStream_t stream)
{
    const float* x     = (const float*)d_in[0];
    const float* wih   = (const float*)d_in[1];
    const float* whh   = (const float*)d_in[2];
    const float* bih   = (const float*)d_in[3];
    const float* bhh   = (const float*)d_in[4];
    const float* wq    = (const float*)d_in[5];
    const float* wk    = (const float*)d_in[6];
    const float* wv    = (const float*)d_in[7];
    const float* wbeat = (const float*)d_in[8];
    const float* ng    = (const float*)d_in[9];
    const float* nb    = (const float*)d_in[10];
    const float* wmix  = (const float*)d_in[11];
    const float* bng   = (const float*)d_in[12];
    const float* bnb   = (const float*)d_in[13];

    char* ws = (char*)d_ws;
    size_t off = 0;
    auto alloc = [&](size_t b) { size_t o = off; off += (b + 255) & ~(size_t)255; return o; };

    const size_t XINBF  = alloc((size_t)BT_ * 512 * 2);        //  8.4 MB
    const size_t WIHBF  = alloc((size_t)4 * 1536 * 512 * 2);   //  6.3 MB
    const size_t WQBF   = alloc((size_t)4 * 512 * 512 * 2);
    const size_t WKBF   = alloc((size_t)4 * 512 * 512 * 2);
    const size_t WVBF   = alloc((size_t)4 * 512 * 512 * 2);
    const size_t WBEATBF= alloc((size_t)4 * 512 * 1024 * 2);
    const size_t WMIXBF = alloc((size_t)512 * 2048 * 2);
    const size_t HBUF   = alloc((size_t)16 * 4 * 512 * 8);     //  256 KB ring
    const size_t COMB   = alloc((size_t)4 * BT_ * 1024 * 2);   // 67.1 MB
    const size_t BIG    = alloc((size_t)4 * BT_ * 1536 * 2);   // 100.7 MB
    const size_t NEED   = off;                                  // ~195 MB

    const size_t XPO   = BIG;                   // phase A: xp (4,8192,1536) bf16
    const size_t QO    = BIG;                   // phase B: Q (4,8192,512) bf16
    const size_t KO    = BIG + 33554432;        //          K
    const size_t VO    = BIG + 67108864;        //          V
    const size_t BEATO = BIG;                   // phase C: beat bf16
    const size_t THRO  = BIG + 33554432;        //          merged thr bf16
    const size_t MIXO  = BIG + 67108864;        //          mix out fp32

    if (ws_size < NEED) {
        k_fill<<<(out_size + 255) / 256, 256, 0, stream>>>((float*)d_out, out_size);
        return;
    }

    hipMemsetAsync(ws + HBUF, 0, (size_t)16 * 4 * 512 * 8, stream);

    k_prep<<<(B_ * T_ * D_ + 255) / 256, 256, 0, stream>>>(x, (__hip_bfloat16*)(ws + XINBF));

    auto cast = [&](const float* s, size_t o, int n) {
        k_f2bf<<<(n + 255) / 256, 256, 0, stream>>>(s, (__hip_bfloat16*)(ws + o), n);
    };
    cast(wih,   WIHBF,  4 * 1536 * 512);
    cast(wq,    WQBF,   4 * 512 * 512);
    cast(wk,    WKBF,   4 * 512 * 512);
    cast(wv,    WVBF,   4 * 512 * 512);
    cast(wbeat, WBEATBF,4 * 512 * 1024);
    cast(wmix,  WMIXBF, 512 * 2048);

    const __hip_bfloat16* xinbf = (const __hip_bfloat16*)(ws + XINBF);

    // xp = wih . xin + bih   (4, 8192, 1536) bf16
    k_gemm<<<dim3(BT_ / 128, 1536 / 128, 4), 256, 0, stream>>>(
        xinbf, (const __hip_bfloat16*)(ws + WIHBF),
        nullptr, (__hip_bfloat16*)(ws + XPO),
        bih, nullptr, BT_, 1536, 512,
        0, (long)1536 * 512, (long)BT_ * 1536, 1536);

    // GRU scan -> comb[.., 0:512]
    k_gru<<<256, 512, 0, stream>>>(
        whh, bhh, (const __hip_bfloat16*)(ws + XPO),
        (unsigned long long*)(ws + HBUF), (__hip_bfloat16*)(ws + COMB));

    // q/k/v projections (xp region is dead)
    k_gemm<<<dim3(BT_ / 128, 4, 4), 256, 0, stream>>>(
        xinbf, (const __hip_bfloat16*)(ws + WQBF), nullptr, (__hip_bfloat16*)(ws + QO),
        nullptr, nullptr, BT_, 512, 512, 0, (long)512 * 512, (long)BT_ * 512, 0);
    k_gemm<<<dim3(BT_ / 128, 4, 4), 256, 0, stream>>>(
        xinbf, (const __hip_bfloat16*)(ws + WKBF), nullptr, (__hip_bfloat16*)(ws + KO),
        nullptr, nullptr, BT_, 512, 512, 0, (long)512 * 512, (long)BT_ * 512, 0);
    k_gemm<<<dim3(BT_ / 128, 4, 4), 256, 0, stream>>>(
        xinbf, (const __hip_bfloat16*)(ws + WVBF), nullptr, (__hip_bfloat16*)(ws + VO),
        nullptr, nullptr, BT_, 512, 512, 0, (long)512 * 512, (long)BT_ * 512, 0);

    // windowed attention -> comb[.., 512:1024]
    k_attn<<<dim3(T_ / 16, 16), 256, 0, stream>>>(
        (const __hip_bfloat16*)(ws + QO), (const __hip_bfloat16*)(ws + KO),
        (const __hip_bfloat16*)(ws + VO), (__hip_bfloat16*)(ws + COMB));

    // beat = w_beat . comb + xin  -> bf16
    k_gemm<<<dim3(BT_ / 128, 4, 4), 256, 0, stream>>>(
        (const __hip_bfloat16*)(ws + COMB), (const __hip_bfloat16*)(ws + WBEATBF),
        nullptr, (__hip_bfloat16*)(ws + BEATO),
        nullptr, xinbf, BT_, 512, 1024,
        (long)BT_ * 1024, (long)512 * 1024, (long)BT_ * 512, 0);

    // per-thread LayerNorm -> merged (8192, 2048) bf16
    k_ln_thr<<<dim3(BT_ / 32, 4), 256, 0, stream>>>(
        (const __hip_bfloat16*)(ws + BEATO), ng, nb, (__hip_bfloat16*)(ws + THRO));

    // out = w_mix . merged (fp32)
    k_gemm<<<dim3(BT_ / 128, 4, 1), 256, 0, stream>>>(
        (const __hip_bfloat16*)(ws + THRO), (const __hip_bfloat16*)(ws + WMIXBF),
        (float*)(ws + MIXO), nullptr,
        nullptr, nullptr, BT_, 512, 2048, 0, 0, 0, 0);

    // final LayerNorm(out + x + pe) -> d_out
    k_ln_fin<<<BT_ / 32, 256, 0, stream>>>(
        (const float*)(ws + MIXO), x, bng, bnb, (float*)d_out);
}